// Round 1
// baseline (809.932 us; speedup 1.0000x reference)
//
#include <hip/hip_runtime.h>

#define SENSOR_W 1024
#define SENSOR_H 1024

__global__ __launch_bounds__(256) void sensor_hist_kernel(
    const float4* __restrict__ x4,
    const float4* __restrict__ y4,
    const float4* __restrict__ v4,
    float* __restrict__ out,
    int n_chunks)
{
    const float X0 = -3.0f;
    const float Y0 = -3.0f;
    const float DX = 6.0f / 1024.0f;   // exactly representable (3/512)
    const float DY = 6.0f / 1024.0f;

    int stride = gridDim.x * blockDim.x;
    for (int i = blockIdx.x * blockDim.x + threadIdx.x; i < n_chunks; i += stride) {
        float4 xv = x4[i];
        float4 yv = y4[i];
        float4 vv = v4[i];

        float xs[4] = {xv.x, xv.y, xv.z, xv.w};
        float ys[4] = {yv.x, yv.y, yv.z, yv.w};
        float vs[4] = {vv.x, vv.y, vv.z, vv.w};

#pragma unroll
        for (int j = 0; j < 4; ++j) {
            // Match reference bit-for-bit: floor((x - X0) / DX), true f32 divide.
            float fx = floorf((xs[j] - X0) / DX);
            float fy = floorf((ys[j] - Y0) / DY);
            // Bounds check in float space (also rejects NaN; avoids int overflow
            // on wild values before the cast).
            if (fx >= 0.0f && fx < (float)SENSOR_W &&
                fy >= 0.0f && fy < (float)SENSOR_H) {
                int xi = (int)fx;
                int yi = (int)fy;
                atomicAdd(&out[yi * SENSOR_W + xi], vs[j]);
            }
        }
    }
}

extern "C" void kernel_launch(void* const* d_in, const int* in_sizes, int n_in,
                              void* d_out, int out_size, void* d_ws, size_t ws_size,
                              hipStream_t stream) {
    const float* x = (const float*)d_in[0];
    const float* y = (const float*)d_in[1];
    const float* v = (const float*)d_in[2];
    float* out = (float*)d_out;

    int n = in_sizes[0];          // 2^24, divisible by 4
    int n_chunks = n / 4;

    // Output is accumulated with atomics -> must start from zero every call
    // (harness poisons d_out once and never re-poisons between replays).
    hipMemsetAsync(out, 0, (size_t)out_size * sizeof(float), stream);

    // Memory-bound: cap grid, grid-stride the rest (G11).
    int block = 256;
    int grid = 4096;  // 1M threads, 4 float4-chunks each
    sensor_hist_kernel<<<grid, block, 0, stream>>>(
        (const float4*)x, (const float4*)y, (const float4*)v, out, n_chunks);
}

// Round 2
// 400.541 us; speedup vs baseline: 2.0221x; 2.0221x over previous
//
#include <hip/hip_runtime.h>
#include <stdint.h>

#define SW 1024
#define SH 1024
#define TSZ 64                 // tile edge in pixels
#define NT  256                // 16x16 tiles
#define N_HITS (1 << 24)
#define B1 2048                // blocks for count/scatter passes
#define HPB (N_HITS / B1)      // 8192 hits per block
#define RND (HPB / 1024)       // 8 rounds (256 thr * 4 hits)
#define CHUNK 32768            // hits per accumulation chunk
#define MAXCH (NT + N_HITS / CHUNK)   // 256 + 512 = 768

// ws layout (u32 words)
#define OFS_CNT   0u
#define OFS_BASE  (OFS_CNT + (uint32_t)B1 * NT)          // 524288
#define OFS_TOTAL (OFS_BASE + (uint32_t)B1 * NT)         // 1048576
#define OFS_BOFF  (OFS_TOTAL + NT)                       // 1048832
#define OFS_CBASE (OFS_BOFF + NT + 1)                    // 1049089
#define OFS_PAIRS 1049346u                               // even -> 8B aligned
#define OFS_PART  (OFS_PAIRS + 2u * N_HITS)              // 34603778
#define WS_WORDS  (OFS_PART + (uint32_t)MAXCH * TSZ * TSZ)
#define WS_BYTES  ((size_t)WS_WORDS * 4u)

__device__ __forceinline__ uint32_t pix_of(float x, float y) {
    // bit-exact match to reference: floor((x - X0)/DX), DX = 6/1024 exact
    float fx = floorf((x + 3.0f) / 0.005859375f);
    float fy = floorf((y + 3.0f) / 0.005859375f);
    if (fx >= 0.0f && fx < 1024.0f && fy >= 0.0f && fy < 1024.0f) {
        return ((uint32_t)(int)fy << 10) | (uint32_t)(int)fx;
    }
    return 0xFFFFFFFFu;
}

// ---- pass 1a: per-(block,bucket) counts --------------------------------
__global__ __launch_bounds__(256) void k_count(const float4* __restrict__ x4,
                                               const float4* __restrict__ y4,
                                               uint32_t* __restrict__ cnt) {
    __shared__ uint32_t lcnt[NT];
    int tid = threadIdx.x, b = blockIdx.x;
    lcnt[tid] = 0;
    __syncthreads();
    int base4 = b * (HPB / 4);
#pragma unroll
    for (int r = 0; r < RND; ++r) {
        float4 xv = x4[base4 + r * 256 + tid];
        float4 yv = y4[base4 + r * 256 + tid];
        float xs[4] = {xv.x, xv.y, xv.z, xv.w};
        float ys[4] = {yv.x, yv.y, yv.z, yv.w};
#pragma unroll
        for (int j = 0; j < 4; ++j) {
            uint32_t p = pix_of(xs[j], ys[j]);
            if (p != 0xFFFFFFFFu) {
                uint32_t t = ((p >> 16) << 4) | ((p & 1023u) >> 6);
                atomicAdd(&lcnt[t], 1u);
            }
        }
    }
    __syncthreads();
    cnt[b * NT + tid] = lcnt[tid];
}

// ---- pass 1b: per-bucket exclusive scan over blocks --------------------
__global__ __launch_bounds__(256) void k_scan_blocks(const uint32_t* __restrict__ cnt,
                                                     uint32_t* __restrict__ base,
                                                     uint32_t* __restrict__ total) {
    __shared__ uint32_t s[256];
    __shared__ uint32_t carry;
    int t = blockIdx.x, tid = threadIdx.x;
    if (tid == 0) carry = 0;
    __syncthreads();
    for (int r = 0; r < B1 / 256; ++r) {
        int b = r * 256 + tid;
        uint32_t v = cnt[b * NT + t];
        s[tid] = v;
        __syncthreads();
        for (int off = 1; off < 256; off <<= 1) {
            uint32_t add = (tid >= off) ? s[tid - off] : 0u;
            __syncthreads();
            s[tid] += add;
            __syncthreads();
        }
        uint32_t incl = s[tid];
        uint32_t c = carry;
        base[b * NT + t] = c + incl - v;
        __syncthreads();
        if (tid == 255) carry = c + incl;
        __syncthreads();
    }
    if (tid == 0) total[t] = carry;
}

// ---- pass 1b2: bucket offsets + chunk bases ----------------------------
__global__ __launch_bounds__(256) void k_scan_tiles(const uint32_t* __restrict__ total,
                                                    uint32_t* __restrict__ boff,
                                                    uint32_t* __restrict__ cbase) {
    __shared__ uint32_t s[256];
    int tid = threadIdx.x;
    uint32_t v = total[tid];
    s[tid] = v;
    __syncthreads();
    for (int off = 1; off < 256; off <<= 1) {
        uint32_t add = (tid >= off) ? s[tid - off] : 0u;
        __syncthreads();
        s[tid] += add;
        __syncthreads();
    }
    boff[tid] = s[tid] - v;
    if (tid == 255) boff[256] = s[255];
    __syncthreads();
    uint32_t cc = (v + CHUNK - 1) / CHUNK;
    if (cc == 0) cc = 1;
    s[tid] = cc;
    __syncthreads();
    for (int off = 1; off < 256; off <<= 1) {
        uint32_t add = (tid >= off) ? s[tid - off] : 0u;
        __syncthreads();
        s[tid] += add;
        __syncthreads();
    }
    cbase[tid] = s[tid] - cc;
    if (tid == 255) cbase[256] = s[255];
}

// ---- pass 1c: scatter (pixel,value) pairs into per-tile lists ----------
__global__ __launch_bounds__(256) void k_scatter(const float4* __restrict__ x4,
                                                 const float4* __restrict__ y4,
                                                 const float4* __restrict__ v4,
                                                 const uint32_t* __restrict__ base,
                                                 const uint32_t* __restrict__ boff,
                                                 uint2* __restrict__ pairs) {
    __shared__ uint32_t lcur[NT];
    int tid = threadIdx.x, b = blockIdx.x;
    lcur[tid] = boff[tid] + base[b * NT + tid];
    __syncthreads();
    int base4 = b * (HPB / 4);
    uint32_t pidx[RND * 4];
#pragma unroll
    for (int r = 0; r < RND; ++r) {
        float4 xv = x4[base4 + r * 256 + tid];
        float4 yv = y4[base4 + r * 256 + tid];
        float xs[4] = {xv.x, xv.y, xv.z, xv.w};
        float ys[4] = {yv.x, yv.y, yv.z, yv.w};
#pragma unroll
        for (int j = 0; j < 4; ++j) pidx[r * 4 + j] = pix_of(xs[j], ys[j]);
    }
#pragma unroll
    for (int r = 0; r < RND; ++r) {
        float4 vv = v4[base4 + r * 256 + tid];
        float vs[4] = {vv.x, vv.y, vv.z, vv.w};
#pragma unroll
        for (int j = 0; j < 4; ++j) {
            uint32_t p = pidx[r * 4 + j];
            if (p != 0xFFFFFFFFu) {
                uint32_t t = ((p >> 16) << 4) | ((p & 1023u) >> 6);
                uint32_t slot = atomicAdd(&lcur[t], 1u);
                pairs[slot] = make_uint2(p, __float_as_uint(vs[j]));
            }
        }
    }
}

// ---- pass 2: per-chunk LDS tile histogram -> partial buffers -----------
__global__ __launch_bounds__(256) void k_accum(const uint2* __restrict__ pairs,
                                               const uint32_t* __restrict__ boff,
                                               const uint32_t* __restrict__ total,
                                               const uint32_t* __restrict__ cbase,
                                               float* __restrict__ partials) {
    __shared__ float hist[TSZ * TSZ];
    int c = blockIdx.x, tid = threadIdx.x;
    uint32_t nch = cbase[NT];
    if ((uint32_t)c >= nch) return;
    int lo = 0, hi = NT - 1;
    while (lo < hi) {
        int mid = (lo + hi + 1) >> 1;
        if (cbase[mid] <= (uint32_t)c) lo = mid; else hi = mid - 1;
    }
    int t = lo;
    uint32_t k = (uint32_t)c - cbase[t];
    uint32_t st = boff[t] + k * (uint32_t)CHUNK;
    uint32_t en = boff[t] + total[t];
    uint32_t en2 = st + (uint32_t)CHUNK;
    if (en2 < en) en = en2;
    for (int i = tid; i < TSZ * TSZ; i += 256) hist[i] = 0.0f;
    __syncthreads();
    for (uint32_t i = st + (uint32_t)tid; i < en; i += 256) {
        uint2 pr = pairs[i];
        uint32_t p = pr.x;
        uint32_t lx = p & 63u;
        uint32_t ly = (p >> 10) & 63u;
        atomicAdd(&hist[ly * TSZ + lx], __uint_as_float(pr.y));
    }
    __syncthreads();
    float* dst = partials + (size_t)c * (TSZ * TSZ);
    for (int i = tid; i < TSZ * TSZ; i += 256) dst[i] = hist[i];
}

// ---- pass 3: reduce partials, write final image (every pixel once) -----
__global__ __launch_bounds__(256) void k_reduce(const float* __restrict__ partials,
                                                const uint32_t* __restrict__ cbase,
                                                float* __restrict__ out) {
    int t = blockIdx.x, tid = threadIdx.x;
    uint32_t c0 = cbase[t], c1 = cbase[t + 1];
    int tx = t & 15, ty = t >> 4;
    for (int i = tid; i < TSZ * TSZ; i += 256) {
        float s = 0.0f;
        for (uint32_t c = c0; c < c1; ++c) s += partials[(size_t)c * (TSZ * TSZ) + i];
        int row = i >> 6, col = i & 63;
        out[(ty * TSZ + row) * SW + tx * TSZ + col] = s;
    }
}

// ---- fallback: direct-atomic version (known-correct, 810 us) -----------
__global__ __launch_bounds__(256) void k_naive(const float4* __restrict__ x4,
                                               const float4* __restrict__ y4,
                                               const float4* __restrict__ v4,
                                               float* __restrict__ out,
                                               int n_chunks) {
    int stride = gridDim.x * blockDim.x;
    for (int i = blockIdx.x * blockDim.x + threadIdx.x; i < n_chunks; i += stride) {
        float4 xv = x4[i];
        float4 yv = y4[i];
        float4 vv = v4[i];
        float xs[4] = {xv.x, xv.y, xv.z, xv.w};
        float ys[4] = {yv.x, yv.y, yv.z, yv.w};
        float vs[4] = {vv.x, vv.y, vv.z, vv.w};
#pragma unroll
        for (int j = 0; j < 4; ++j) {
            uint32_t p = pix_of(xs[j], ys[j]);
            if (p != 0xFFFFFFFFu) atomicAdd(&out[(p >> 10) * SW + (p & 1023u)], vs[j]);
        }
    }
}

extern "C" void kernel_launch(void* const* d_in, const int* in_sizes, int n_in,
                              void* d_out, int out_size, void* d_ws, size_t ws_size,
                              hipStream_t stream) {
    const float* x = (const float*)d_in[0];
    const float* y = (const float*)d_in[1];
    const float* v = (const float*)d_in[2];
    float* out = (float*)d_out;
    int n = in_sizes[0];

    if (n == N_HITS && ws_size >= WS_BYTES) {
        uint32_t* w = (uint32_t*)d_ws;
        uint32_t* cnt   = w + OFS_CNT;
        uint32_t* base  = w + OFS_BASE;
        uint32_t* total = w + OFS_TOTAL;
        uint32_t* boff  = w + OFS_BOFF;
        uint32_t* cbase = w + OFS_CBASE;
        uint2*    pairs = (uint2*)(w + OFS_PAIRS);
        float*    parts = (float*)(w + OFS_PART);

        k_count<<<B1, 256, 0, stream>>>((const float4*)x, (const float4*)y, cnt);
        k_scan_blocks<<<NT, 256, 0, stream>>>(cnt, base, total);
        k_scan_tiles<<<1, 256, 0, stream>>>(total, boff, cbase);
        k_scatter<<<B1, 256, 0, stream>>>((const float4*)x, (const float4*)y,
                                          (const float4*)v, base, boff, pairs);
        k_accum<<<MAXCH, 256, 0, stream>>>(pairs, boff, total, cbase, parts);
        k_reduce<<<NT, 256, 0, stream>>>(parts, cbase, out);
    } else {
        hipMemsetAsync(out, 0, (size_t)out_size * sizeof(float), stream);
        k_naive<<<4096, 256, 0, stream>>>((const float4*)x, (const float4*)y,
                                          (const float4*)v, out, n / 4);
    }
}

// Round 3
// 362.749 us; speedup vs baseline: 2.2328x; 1.1042x over previous
//
#include <hip/hip_runtime.h>
#include <stdint.h>

#define SW 1024
#define NB 64                    // 64 bands x 16 rows
#define N_HITS (1 << 24)
#define B1 2048                  // blocks for count/scatter
#define HPB (N_HITS / B1)        // 8192 hits per block
#define RND (HPB / 1024)         // 8 rounds (256 thr * 4)
#define CHUNK 131072             // hits per accumulation chunk
#define MAXCH (NB + N_HITS / CHUNK)   // 64 + 128 = 192

// ws layout (u32 words)
#define OFS_CNT   0u
#define OFS_BASE  (OFS_CNT + (uint32_t)B1 * NB)      // 131072
#define OFS_TOTAL (OFS_BASE + (uint32_t)B1 * NB)     // 262144
#define OFS_BOFF  (OFS_TOTAL + NB)                   // 262208
#define OFS_CBASE (OFS_BOFF + NB + 1)                // 262273
#define OFS_PAIRS 262338u                            // even -> 8B aligned
#define OFS_PART  (OFS_PAIRS + 2u * N_HITS)          // 33816770
#define WS_WORDS  (OFS_PART + (uint32_t)MAXCH * 16384u)   // ~147.9 MB
#define WS_BYTES  ((size_t)WS_WORDS * 4u)

#define INV_D 0.005859375f       // 6/1024, exact

__device__ __forceinline__ uint32_t pix_of(float x, float y) {
    float fx = floorf((x + 3.0f) / INV_D);
    float fy = floorf((y + 3.0f) / INV_D);
    if (fx >= 0.0f && fx < 1024.0f && fy >= 0.0f && fy < 1024.0f) {
        return ((uint32_t)(int)fy << 10) | (uint32_t)(int)fx;
    }
    return 0xFFFFFFFFu;
}

// ---- pass 1a: per-(block,band) counts from y only ----------------------
__global__ __launch_bounds__(256) void k_count(const float4* __restrict__ y4,
                                               uint32_t* __restrict__ cnt) {
    __shared__ uint32_t lcnt[4 * NB];   // per-wave counters to cut contention
    int tid = threadIdx.x, b = blockIdx.x;
    int wave = tid >> 6;
    lcnt[tid] = 0;
    __syncthreads();
    int base4 = b * (HPB / 4);
#pragma unroll
    for (int r = 0; r < RND; ++r) {
        float4 yv = y4[base4 + r * 256 + tid];
        float ys[4] = {yv.x, yv.y, yv.z, yv.w};
#pragma unroll
        for (int j = 0; j < 4; ++j) {
            float fy = floorf((ys[j] + 3.0f) / INV_D);
            if (fy >= 0.0f && fy < 1024.0f) {
                atomicAdd(&lcnt[wave * NB + ((int)fy >> 4)], 1u);
            }
        }
    }
    __syncthreads();
    if (tid < NB)
        cnt[b * NB + tid] = lcnt[tid] + lcnt[NB + tid] + lcnt[2 * NB + tid] + lcnt[3 * NB + tid];
}

// ---- pass 1b: per-band exclusive scan over blocks ----------------------
__global__ __launch_bounds__(256) void k_scan_blocks(const uint32_t* __restrict__ cnt,
                                                     uint32_t* __restrict__ base,
                                                     uint32_t* __restrict__ total) {
    __shared__ uint32_t s[256];
    __shared__ uint32_t carry;
    int t = blockIdx.x, tid = threadIdx.x;
    if (tid == 0) carry = 0;
    __syncthreads();
    for (int r = 0; r < B1 / 256; ++r) {
        int b = r * 256 + tid;
        uint32_t v = cnt[b * NB + t];
        s[tid] = v;
        __syncthreads();
        for (int off = 1; off < 256; off <<= 1) {
            uint32_t add = (tid >= off) ? s[tid - off] : 0u;
            __syncthreads();
            s[tid] += add;
            __syncthreads();
        }
        uint32_t incl = s[tid];
        uint32_t c = carry;
        base[b * NB + t] = c + incl - v;
        __syncthreads();
        if (tid == 255) carry = c + incl;
        __syncthreads();
    }
    if (tid == 0) total[t] = carry;
}

// ---- pass 1b2: band offsets + chunk bases (serial, 64 elems, trivial) --
__global__ __launch_bounds__(64) void k_scan_bands(const uint32_t* __restrict__ total,
                                                   uint32_t* __restrict__ boff,
                                                   uint32_t* __restrict__ cbase) {
    if (threadIdx.x == 0 && blockIdx.x == 0) {
        uint32_t acc = 0, cacc = 0;
        for (int i = 0; i < NB; ++i) {
            boff[i] = acc;
            cbase[i] = cacc;
            uint32_t v = total[i];
            acc += v;
            uint32_t cc = (v + CHUNK - 1) / CHUNK;
            cacc += (cc == 0) ? 1u : cc;
        }
        boff[NB] = acc;
        cbase[NB] = cacc;
    }
}

// ---- pass 1c: scatter (pixel,value) pairs into per-band lists ----------
__global__ __launch_bounds__(256) void k_scatter(const float4* __restrict__ x4,
                                                 const float4* __restrict__ y4,
                                                 const float4* __restrict__ v4,
                                                 const uint32_t* __restrict__ base,
                                                 const uint32_t* __restrict__ boff,
                                                 uint2* __restrict__ pairs) {
    __shared__ uint32_t lcur[NB];
    int tid = threadIdx.x, b = blockIdx.x;
    if (tid < NB) lcur[tid] = boff[tid] + base[b * NB + tid];
    __syncthreads();
    int base4 = b * (HPB / 4);
#pragma unroll
    for (int r = 0; r < RND; ++r) {
        float4 xv = x4[base4 + r * 256 + tid];
        float4 yv = y4[base4 + r * 256 + tid];
        float4 vv = v4[base4 + r * 256 + tid];
        float xs[4] = {xv.x, xv.y, xv.z, xv.w};
        float ys[4] = {yv.x, yv.y, yv.z, yv.w};
        float vs[4] = {vv.x, vv.y, vv.z, vv.w};
#pragma unroll
        for (int j = 0; j < 4; ++j) {
            float fy = floorf((ys[j] + 3.0f) / INV_D);
            if (fy >= 0.0f && fy < 1024.0f) {
                int yi = (int)fy;
                float fx = floorf((xs[j] + 3.0f) / INV_D);
                bool xok = (fx >= 0.0f && fx < 1024.0f);
                uint32_t p = ((uint32_t)yi << 10) | (xok ? (uint32_t)(int)fx : 0u);
                float val = xok ? vs[j] : 0.0f;
                uint32_t slot = atomicAdd(&lcur[yi >> 4], 1u);
                pairs[slot] = make_uint2(p, __float_as_uint(val));
            }
        }
    }
}

// ---- pass 2: per-chunk LDS band histogram (16x1024) --------------------
__global__ __launch_bounds__(512) void k_accum(const uint2* __restrict__ pairs,
                                               const uint32_t* __restrict__ boff,
                                               const uint32_t* __restrict__ cbase,
                                               float* __restrict__ partials) {
    __shared__ float hist[16 * 1024];   // 64 KB
    int c = blockIdx.x, tid = threadIdx.x;
    uint32_t nch = cbase[NB];
    if ((uint32_t)c >= nch) return;
    int lo = 0, hi = NB - 1;
    while (lo < hi) {
        int mid = (lo + hi + 1) >> 1;
        if (cbase[mid] <= (uint32_t)c) lo = mid; else hi = mid - 1;
    }
    int t = lo;
    uint32_t k = (uint32_t)c - cbase[t];
    uint32_t st = boff[t] + k * (uint32_t)CHUNK;
    uint32_t en = boff[t + 1];
    uint32_t en2 = st + (uint32_t)CHUNK;
    if (en2 < en) en = en2;
    for (int i = tid; i < 16 * 1024; i += 512) hist[i] = 0.0f;
    __syncthreads();
    for (uint32_t i = st + (uint32_t)tid; i < en; i += 512) {
        uint2 pr = pairs[i];
        uint32_t p = pr.x;
        uint32_t lx = p & 1023u;
        uint32_t ly = (p >> 10) & 15u;
        atomicAdd(&hist[ly * 1024 + lx], __uint_as_float(pr.y));
    }
    __syncthreads();
    float4* dst = (float4*)(partials + (size_t)c * (16 * 1024));
    const float4* src = (const float4*)hist;
    for (int i = tid; i < 4 * 1024; i += 512) dst[i] = src[i];
}

// ---- pass 3: reduce partials, write final image (every pixel once) -----
__global__ __launch_bounds__(256) void k_reduce(const float* __restrict__ partials,
                                                const uint32_t* __restrict__ cbase,
                                                float* __restrict__ out) {
    int t = blockIdx.x, tid = threadIdx.x;
    uint32_t c0 = cbase[t], c1 = cbase[t + 1];
    float4* o4 = (float4*)(out + (size_t)t * (16 * 1024));
    for (int i = tid; i < 4 * 1024; i += 256) {
        float4 s = make_float4(0.f, 0.f, 0.f, 0.f);
        for (uint32_t c = c0; c < c1; ++c) {
            float4 p = ((const float4*)(partials + (size_t)c * (16 * 1024)))[i];
            s.x += p.x; s.y += p.y; s.z += p.z; s.w += p.w;
        }
        o4[i] = s;
    }
}

// ---- fallback: direct-atomic version (known-correct) -------------------
__global__ __launch_bounds__(256) void k_naive(const float4* __restrict__ x4,
                                               const float4* __restrict__ y4,
                                               const float4* __restrict__ v4,
                                               float* __restrict__ out,
                                               int n_chunks) {
    int stride = gridDim.x * blockDim.x;
    for (int i = blockIdx.x * blockDim.x + threadIdx.x; i < n_chunks; i += stride) {
        float4 xv = x4[i];
        float4 yv = y4[i];
        float4 vv = v4[i];
        float xs[4] = {xv.x, xv.y, xv.z, xv.w};
        float ys[4] = {yv.x, yv.y, yv.z, yv.w};
        float vs[4] = {vv.x, vv.y, vv.z, vv.w};
#pragma unroll
        for (int j = 0; j < 4; ++j) {
            uint32_t p = pix_of(xs[j], ys[j]);
            if (p != 0xFFFFFFFFu) atomicAdd(&out[(p >> 10) * SW + (p & 1023u)], vs[j]);
        }
    }
}

extern "C" void kernel_launch(void* const* d_in, const int* in_sizes, int n_in,
                              void* d_out, int out_size, void* d_ws, size_t ws_size,
                              hipStream_t stream) {
    const float* x = (const float*)d_in[0];
    const float* y = (const float*)d_in[1];
    const float* v = (const float*)d_in[2];
    float* out = (float*)d_out;
    int n = in_sizes[0];

    if (n == N_HITS && ws_size >= WS_BYTES) {
        uint32_t* w = (uint32_t*)d_ws;
        uint32_t* cnt   = w + OFS_CNT;
        uint32_t* base  = w + OFS_BASE;
        uint32_t* total = w + OFS_TOTAL;
        uint32_t* boff  = w + OFS_BOFF;
        uint32_t* cbase = w + OFS_CBASE;
        uint2*    pairs = (uint2*)(w + OFS_PAIRS);
        float*    parts = (float*)(w + OFS_PART);

        k_count<<<B1, 256, 0, stream>>>((const float4*)y, cnt);
        k_scan_blocks<<<NB, 256, 0, stream>>>(cnt, base, total);
        k_scan_bands<<<1, 64, 0, stream>>>(total, boff, cbase);
        k_scatter<<<B1, 256, 0, stream>>>((const float4*)x, (const float4*)y,
                                          (const float4*)v, base, boff, pairs);
        k_accum<<<MAXCH, 512, 0, stream>>>(pairs, boff, cbase, parts);
        k_reduce<<<NB, 256, 0, stream>>>(parts, cbase, out);
    } else {
        hipMemsetAsync(out, 0, (size_t)out_size * sizeof(float), stream);
        k_naive<<<4096, 256, 0, stream>>>((const float4*)x, (const float4*)y,
                                          (const float4*)v, out, n / 4);
    }
}